// Round 4
// baseline (594.627 us; speedup 1.0000x reference)
//
#include <hip/hip_runtime.h>

// Problem geometry (fixed by reference)
#define WINS 7
#define H 160
#define W 160
#define DD 96
#define HO 154          // H - WINS + 1
#define WO 154
#define DOUT 90
#define CSTRIDE (H*W*DD)   // per-(b,c) channel stride

// Tile config: 8x8x8 outputs per block, 4 blocks/CU (LDS ~40.5 KB)
#define TH 8
#define TW 8
#define TD 8
#define IH 14            // TH + WINS - 1
#define IW 14
#define NCOL (IH * IW)   // 196
#define IDU 14           // used d extent = TD + WINS - 1
#define ID 16            // staged d extent (padded to 4 x float4)
#define NV 4             // float4s per column
#define HTILES 20
#define WTILES 20
#define DTILES 12        // ceil(90/8) = 12 (last tile: 2 valid d-outputs)
#define NBC 8            // B*C
#define DPB 15           // sB dd-stride in f4 (14 + 1 pad)

__device__ __forceinline__ float sval(float c0, float c1, float c2) {
    // c0=S_m, c1=S_tm, c2=S_t2m over the 343-voxel window; t = m?sigmoid:0.5
    const float S_t  = c1 + 0.5f  * (343.0f - c0);
    const float S_t2 = c2 + 0.25f * (343.0f - c0);
    const float inv  = 1.0f / 343.0f;
    const float ux   = S_t  * inv;
    const float uy   = c0   * inv;
    const float uxx  = S_t2 * inv;
    const float uxy  = c1   * inv;
    const float covn = 49.0f / 48.0f;   // WIN^2/(WIN^2-1)
    const float cc   = 0.00045f;        // (0.03*data_range)^2/2, data_range==1
    const float vx  = covn * (uxx - ux * ux);
    const float vy  = covn * (uy  - uy * uy);
    const float vxy = covn * (uxy - ux * uy);
    return (vxy + cc) / (vx * vy + cc);
}

__global__ __launch_bounds__(256)
void structure_loss_main(const float* __restrict__ x,
                         const int* __restrict__ y,
                         double* __restrict__ acc) {
    // sA: W-window sums packed f4 [ih][wo][dd]: 14*8*14*16 = 25,088 B
    __shared__ float4 sA[IH * TW * IDU];
    // vs (phase 0/A) and sB (phase B/C) are never live together
    __shared__ union {
        float  vs[NCOL * ID];        // 12,544 B ; v = (y==cl ? +sig : -sig)
        float4 sB[TH * TW * DPB];    // 15,360 B ; H-window sums [ho][wo][dd(pad)]
    } u;
    __shared__ float wsum[4];

    const int dt = blockIdx.x;                 // 0..11
    const int wt = blockIdx.y;                 // 0..19
    const int z  = blockIdx.z;                 // 0..159
    const int bc = z / HTILES;
    const int ht = z - bc * HTILES;
    const int b  = bc >> 2;
    const int cl = bc & 3;

    const int h0 = ht * TH, w0 = wt * TW, d0 = dt * TD;

    const float* xc = x + ((size_t)b * 4 + cl) * (size_t)CSTRIDE;
    const int*   yc = y + (size_t)b * (size_t)CSTRIDE;

    const int t = threadIdx.x;

    // ---- Phase 0: coalesced vector staging. sign bit = one-hot mask ----
    for (int i = t; i < NCOL * NV; i += 256) {          // 784 float4-items
        const int col = i >> 2, q = i & 3;
        const int ih = col / IW, iw = col - ih * IW;
        const int h = min(h0 + ih, H - 1);
        const int w = min(w0 + iw, W - 1);
        const int dbase = d0 + 4 * q;
        float4 vv;
        if (dbase < DD) {
            const size_t off = ((size_t)h * W + w) * DD + dbase;
            const float4 xv = *(const float4*)(xc + off);
            const int4   yv = *(const int4*)(yc + off);
            const float s0 = 1.0f / (1.0f + __expf(-xv.x));
            const float s1 = 1.0f / (1.0f + __expf(-xv.y));
            const float s2 = 1.0f / (1.0f + __expf(-xv.z));
            const float s3 = 1.0f / (1.0f + __expf(-xv.w));
            vv.x = (yv.x == cl) ? s0 : -s0;
            vv.y = (yv.y == cl) ? s1 : -s1;
            vv.z = (yv.z == cl) ? s2 : -s2;
            vv.w = (yv.w == cl) ? s3 : -s3;
        } else {
            vv = make_float4(0.f, 0.f, 0.f, 0.f);   // feeds only discarded outputs
        }
        *(float4*)&u.vs[col * ID + 4 * q] = vv;
    }
    __syncthreads();

    // ---- Phase A: W-window, slide over iw in registers. 196 threads (ih,dd) ----
    if (t < IH * IDU) {
        const int ih = t / IDU, dd = t - ih * IDU;
        float v[IW];
#pragma unroll
        for (int iw = 0; iw < IW; iw++) v[iw] = u.vs[(ih * IW + iw) * ID + dd];
        float s0 = 0.f, s1 = 0.f, s2 = 0.f;
#pragma unroll
        for (int iw = 0; iw < WINS; iw++) {
            const float p = fmaxf(v[iw], 0.f);
            s0 += (v[iw] > 0.f) ? 1.f : 0.f;
            s1 += p;
            s2 += p * v[iw];
        }
        sA[(ih * TW + 0) * IDU + dd] = make_float4(s0, s1, s2, 0.f);
#pragma unroll
        for (int wo = 1; wo < TW; wo++) {
            const float a = v[wo + 6], bb = v[wo - 1];
            const float pa_ = fmaxf(a, 0.f), pb_ = fmaxf(bb, 0.f);
            s0 += ((a > 0.f) ? 1.f : 0.f) - ((bb > 0.f) ? 1.f : 0.f);
            s1 += pa_ - pb_;
            s2 += pa_ * a - pb_ * bb;
            sA[(ih * TW + wo) * IDU + dd] = make_float4(s0, s1, s2, 0.f);
        }
    }
    __syncthreads();   // sA ready; vs reads retired before sB overwrites the union

    // ---- Phase B: H-window, slide 4 outputs. 224 threads (hoHalf, wo, dd) ----
    if (t < 2 * TW * IDU) {
        const int dd = t % IDU;
        const int r  = t / IDU;
        const int wo = r & 7;
        const int ho0 = (r >> 3) * 4;          // 0 or 4
        float4 f[10];
#pragma unroll
        for (int k = 0; k < 10; k++) f[k] = sA[((ho0 + k) * TW + wo) * IDU + dd];
        float s0 = 0.f, s1 = 0.f, s2 = 0.f;
#pragma unroll
        for (int k = 0; k < WINS; k++) { s0 += f[k].x; s1 += f[k].y; s2 += f[k].z; }
        u.sB[(ho0 * TW + wo) * DPB + dd] = make_float4(s0, s1, s2, 0.f);
#pragma unroll
        for (int k = 1; k < 4; k++) {
            s0 += f[k + 6].x - f[k - 1].x;
            s1 += f[k + 6].y - f[k - 1].y;
            s2 += f[k + 6].z - f[k - 1].z;
            u.sB[((ho0 + k) * TW + wo) * DPB + dd] = make_float4(s0, s1, s2, 0.f);
        }
    }
    __syncthreads();

    // ---- Phase C: D-window, slide 2 outputs. 256 threads (ho, wo, dq) ----
    float lsum = 0.f;
    {
        const int dq = t & 3;          // d-quarter: outputs dn = 2*dq, 2*dq+1
        const int wo = (t >> 2) & 7;
        const int ho = t >> 5;
        const int hg = h0 + ho, wg = w0 + wo;
        if (hg < HO && wg < WO) {
            const int base = (ho * TW + wo) * DPB + 2 * dq;
            float4 f[8];
#pragma unroll
            for (int k = 0; k < 8; k++) f[k] = u.sB[base + k];
            float s0 = 0.f, s1 = 0.f, s2 = 0.f;
#pragma unroll
            for (int k = 0; k < WINS; k++) { s0 += f[k].x; s1 += f[k].y; s2 += f[k].z; }
            const int dg = d0 + 2 * dq;
            if (dg < DOUT) lsum += sval(s0, s1, s2);
            s0 += f[7].x - f[0].x;
            s1 += f[7].y - f[0].y;
            s2 += f[7].z - f[0].z;
            if (dg + 1 < DOUT) lsum += sval(s0, s1, s2);
        }
    }

    // wave(64) shuffle reduce, then cross-wave via LDS, one atomic per block
#pragma unroll
    for (int off = 32; off > 0; off >>= 1) lsum += __shfl_down(lsum, off, 64);
    const int wave = t >> 6;
    if ((t & 63) == 0) wsum[wave] = lsum;
    __syncthreads();
    if (t == 0) {
        const float s = wsum[0] + wsum[1] + wsum[2] + wsum[3];
        atomicAdd(acc, (double)s);
    }
}

__global__ void structure_loss_finalize(const double* __restrict__ acc,
                                        float* __restrict__ out) {
    out[0] = 1.0f - (float)(acc[0] / 17075520.0);   // 8*154*154*90
}

extern "C" void kernel_launch(void* const* d_in, const int* in_sizes, int n_in,
                              void* d_out, int out_size, void* d_ws, size_t ws_size,
                              hipStream_t stream) {
    const float* x = (const float*)d_in[0];
    const int*   y = (const int*)d_in[1];
    double* acc = (double*)d_ws;

    hipMemsetAsync(d_ws, 0, sizeof(double), stream);

    dim3 grid(DTILES, WTILES, NBC * HTILES);   // (12, 20, 160) = 38,400 blocks
    structure_loss_main<<<grid, 256, 0, stream>>>(x, y, acc);
    structure_loss_finalize<<<1, 1, 0, stream>>>(acc, (float*)d_out);
}

// Round 5
// 290.696 us; speedup vs baseline: 2.0455x; 2.0455x over previous
//
#include <hip/hip_runtime.h>

// Problem geometry (fixed by reference)
#define WINS 7
#define H 160
#define W 160
#define DD 96
#define HO 154          // H - WINS + 1
#define WO 154
#define DOUT 90
#define CSTRIDE (H*W*DD)   // per-(b,c) channel stride

// Tile: 8x8x16 outputs, all 4 classes per block (y staged once)
#define TH 8
#define TW 8
#define TD 16
#define IH 14            // TH + WINS - 1
#define IW 14
#define NCOL (IH * IW)   // 196
#define IDU 22           // used d extent = TD + WINS - 1
#define ID 24            // staged d extent (6 x float4)
#define NV 6             // float4s / packed-y u32s per column
#define HTILES 20
#define WTILES 20
#define DTILES 6
#define DPB 23           // sB plane dd-stride (22 + 1 pad)

__device__ __forceinline__ float sval(float c0, float c1, float c2) {
    // c0=S_m, c1=S_tm, c2=S_t2m over the 343-voxel window; t = m?sigmoid:0.5
    const float S_t  = c1 + 0.5f  * (343.0f - c0);
    const float S_t2 = c2 + 0.25f * (343.0f - c0);
    const float inv  = 1.0f / 343.0f;
    const float ux   = S_t  * inv;
    const float uy   = c0   * inv;
    const float uxx  = S_t2 * inv;
    const float uxy  = c1   * inv;
    const float covn = 49.0f / 48.0f;   // WIN^2/(WIN^2-1)
    const float cc   = 0.00045f;        // (0.03*data_range)^2/2, data_range==1
    const float vx  = covn * (uxx - ux * ux);
    const float vy  = covn * (uy  - uy * uy);
    const float vxy = covn * (uxy - ux * uy);
    return (vxy + cc) / (vx * vy + cc);
}

__global__ __launch_bounds__(256)
void structure_loss_main(const float* __restrict__ x,
                         const int* __restrict__ y,
                         double* __restrict__ acc) {
    // W-window sums, SoA planes [ih][wo][dd]: 3 * 14*8*22*4 = 29,568 B
    __shared__ float sA0[IH * TW * IDU];
    __shared__ float sA1[IH * TW * IDU];
    __shared__ float sA2[IH * TW * IDU];
    // vs (phase 0/A input) and sB (phase B/C) never live together: 18,816 B
    __shared__ union __align__(16) {
        float vs[NCOL * ID];           // v = (y==cl ? +sig : -sig)
        float sB[3][TH * TW * DPB];    // H-window sums, SoA [ho][wo][dd(pad)]
    } u;
    __shared__ unsigned int yb[NCOL * NV];   // packed y bytes (4 d per u32): 4,704 B
    __shared__ float wsum[4];

    const int dt = blockIdx.x;                 // 0..5
    const int wt = blockIdx.y;                 // 0..19
    const int z  = blockIdx.z;                 // 0..39 = b*HTILES + ht
    const int b  = z / HTILES;
    const int ht = z - b * HTILES;

    const int h0 = ht * TH, w0 = wt * TW, d0 = dt * TD;
    const int* yc = y + (size_t)b * (size_t)CSTRIDE;
    const int t = threadIdx.x;

    // ---- Phase Y: stage packed y tile once (reused by all 4 classes) ----
    for (int i = t; i < NCOL * NV; i += 256) {          // 1176 items
        const int col = i / NV, q = i - col * NV;
        const int ih = col / IW, iw = col - ih * IW;
        const int h = min(h0 + ih, H - 1);
        const int w = min(w0 + iw, W - 1);
        const int dbase = d0 + 4 * q;
        unsigned int pk = 0xFFFFFFFFu;                  // OOB: matches no class
        if (dbase < DD) {
            const int4 yv = *(const int4*)(yc + ((size_t)h * W + w) * DD + dbase);
            pk = (unsigned)(yv.x & 255) | ((unsigned)(yv.y & 255) << 8)
               | ((unsigned)(yv.z & 255) << 16) | ((unsigned)(yv.w & 255) << 24);
        }
        yb[i] = pk;
    }
    __syncthreads();

    float lsum = 0.f;

    for (int cl = 0; cl < 4; cl++) {
        const float* xc = x + ((size_t)b * 4 + cl) * (size_t)CSTRIDE;

        // ---- Phase 0: stage x channel, fuse with staged y. sign bit = mask ----
        for (int i = t; i < NCOL * NV; i += 256) {
            const int col = i / NV, q = i - col * NV;
            const int ih = col / IW, iw = col - ih * IW;
            const int h = min(h0 + ih, H - 1);
            const int w = min(w0 + iw, W - 1);
            const int dbase = d0 + 4 * q;
            float4 vv = make_float4(0.f, 0.f, 0.f, 0.f);
            if (dbase < DD) {
                const float4 xv = *(const float4*)(xc + ((size_t)h * W + w) * DD + dbase);
                const unsigned int pk = yb[i];
                const float s0 = 1.0f / (1.0f + __expf(-xv.x));
                const float s1 = 1.0f / (1.0f + __expf(-xv.y));
                const float s2 = 1.0f / (1.0f + __expf(-xv.z));
                const float s3 = 1.0f / (1.0f + __expf(-xv.w));
                vv.x = ((int)( pk        & 255u) == cl) ? s0 : -s0;
                vv.y = ((int)((pk >>  8) & 255u) == cl) ? s1 : -s1;
                vv.z = ((int)((pk >> 16) & 255u) == cl) ? s2 : -s2;
                vv.w = ((int)((pk >> 24) & 255u) == cl) ? s3 : -s3;
            }
            *(float4*)&u.vs[col * ID + 4 * q] = vv;
        }
        __syncthreads();

        // ---- Phase A: W-window, slide over iw in registers. 308 items (ih,dd) ----
        for (int j = t; j < IH * IDU; j += 256) {
            const int ih = j / IDU, dd = j - ih * IDU;
            float v[IW];
#pragma unroll
            for (int iw = 0; iw < IW; iw++) v[iw] = u.vs[(ih * IW + iw) * ID + dd];
            float s0 = 0.f, s1 = 0.f, s2 = 0.f;
#pragma unroll
            for (int iw = 0; iw < WINS; iw++) {
                const float p = fmaxf(v[iw], 0.f);
                s0 += (v[iw] > 0.f) ? 1.f : 0.f;
                s1 += p;
                s2 += p * v[iw];
            }
            int o = (ih * TW + 0) * IDU + dd;
            sA0[o] = s0; sA1[o] = s1; sA2[o] = s2;
#pragma unroll
            for (int wo = 1; wo < TW; wo++) {
                const float a = v[wo + 6], bb = v[wo - 1];
                const float pa_ = fmaxf(a, 0.f), pb_ = fmaxf(bb, 0.f);
                s0 += ((a > 0.f) ? 1.f : 0.f) - ((bb > 0.f) ? 1.f : 0.f);
                s1 += pa_ - pb_;
                s2 += pa_ * a - pb_ * bb;
                o += IDU;
                sA0[o] = s0; sA1[o] = s1; sA2[o] = s2;
            }
        }
        __syncthreads();   // sA ready; vs reads retired before sB overwrites union

        // ---- Phase B: H-window, slide 4 outputs. 352 items (hoHalf,wo,dd) ----
        for (int j = t; j < 2 * TW * IDU; j += 256) {
            const int dd = j % IDU;
            const int r  = j / IDU;
            const int wo = r & 7;
            const int ho0 = (r >> 3) * 4;          // 0 or 4
            float a0[10], a1[10], a2[10];
#pragma unroll
            for (int k = 0; k < 10; k++) {
                const int idx = ((ho0 + k) * TW + wo) * IDU + dd;
                a0[k] = sA0[idx]; a1[k] = sA1[idx]; a2[k] = sA2[idx];
            }
            float s0 = 0.f, s1 = 0.f, s2 = 0.f;
#pragma unroll
            for (int k = 0; k < WINS; k++) { s0 += a0[k]; s1 += a1[k]; s2 += a2[k]; }
            int o = (ho0 * TW + wo) * DPB + dd;
            u.sB[0][o] = s0; u.sB[1][o] = s1; u.sB[2][o] = s2;
#pragma unroll
            for (int k = 1; k < 4; k++) {
                s0 += a0[k + 6] - a0[k - 1];
                s1 += a1[k + 6] - a1[k - 1];
                s2 += a2[k + 6] - a2[k - 1];
                o += TW * DPB;
                u.sB[0][o] = s0; u.sB[1][o] = s1; u.sB[2][o] = s2;
            }
        }
        __syncthreads();

        // ---- Phase C: D-window, slide 8 outputs. 128 threads (ho,wo,dhalf) ----
        if (t < 128) {
            const int dhalf = t & 1;               // d outputs dhalf*8 .. +7
            const int wo = (t >> 1) & 7;
            const int ho = t >> 4;
            const int hg = h0 + ho, wg = w0 + wo;
            if (hg < HO && wg < WO) {
                const int base = (ho * TW + wo) * DPB + dhalf * 8;
                float b0[14], b1[14], b2[14];
#pragma unroll
                for (int k = 0; k < 14; k++) {
                    b0[k] = u.sB[0][base + k];
                    b1[k] = u.sB[1][base + k];
                    b2[k] = u.sB[2][base + k];
                }
                float s0 = 0.f, s1 = 0.f, s2 = 0.f;
#pragma unroll
                for (int k = 0; k < WINS; k++) { s0 += b0[k]; s1 += b1[k]; s2 += b2[k]; }
#pragma unroll
                for (int k = 0; k < 8; k++) {
                    if (k > 0) {
                        s0 += b0[k + 6] - b0[k - 1];
                        s1 += b1[k + 6] - b1[k - 1];
                        s2 += b2[k + 6] - b2[k - 1];
                    }
                    if (d0 + dhalf * 8 + k < DOUT) lsum += sval(s0, s1, s2);
                }
            }
        }
        __syncthreads();   // retire sB reads before next class overwrites union
    }

    // wave(64) shuffle reduce, then cross-wave via LDS, one atomic per block
#pragma unroll
    for (int off = 32; off > 0; off >>= 1) lsum += __shfl_down(lsum, off, 64);
    const int wave = t >> 6;
    if ((t & 63) == 0) wsum[wave] = lsum;
    __syncthreads();
    if (t == 0) {
        const float s = wsum[0] + wsum[1] + wsum[2] + wsum[3];
        atomicAdd(acc, (double)s);
    }
}

__global__ void structure_loss_finalize(const double* __restrict__ acc,
                                        float* __restrict__ out) {
    out[0] = 1.0f - (float)(acc[0] / 17075520.0);   // 8*154*154*90
}

extern "C" void kernel_launch(void* const* d_in, const int* in_sizes, int n_in,
                              void* d_out, int out_size, void* d_ws, size_t ws_size,
                              hipStream_t stream) {
    const float* x = (const float*)d_in[0];
    const int*   y = (const int*)d_in[1];
    double* acc = (double*)d_ws;

    hipMemsetAsync(d_ws, 0, sizeof(double), stream);

    dim3 grid(DTILES, WTILES, 2 * HTILES);   // (6, 20, 40) = 4,800 blocks
    structure_loss_main<<<grid, 256, 0, stream>>>(x, y, acc);
    structure_loss_finalize<<<1, 1, 0, stream>>>(acc, (float*)d_out);
}

// Round 6
// 257.809 us; speedup vs baseline: 2.3065x; 1.1276x over previous
//
#include <hip/hip_runtime.h>
#include <hip/hip_fp16.h>

// Problem geometry (fixed by reference)
#define WINS 7
#define H 160
#define W 160
#define DD 96
#define HO 154          // H - WINS + 1
#define WO 154
#define DOUT 90
#define CSTRIDE (H*W*DD)   // per-(b,c) channel stride

// Tile: 8x8x16 outputs, all 4 classes per block (y staged once)
#define TH 8
#define TW 8
#define TD 16
#define IH 14            // TH + WINS - 1
#define IW 14
#define NCOL (IH * IW)   // 196
#define IDU 22           // used d extent = TD + WINS - 1
#define ID 24            // staged d extent per column (halfs; 6 x half4)
#define NV 6             // half4-items / packed-y u32s per column
#define NITEMS (NCOL * NV)   // 1176
#define HTILES 20
#define WTILES 20
#define DTILES 6
#define DPB 23           // sB plane dd-stride (22 + 1 pad)

struct alignas(8) Half4 { __half x, y, z, w; };

__device__ __forceinline__ float sval(float c0, float c1, float c2) {
    // c0=S_m, c1=S_tm, c2=S_t2m over the 343-voxel window; t = m?sigmoid:0.5
    const float S_t  = c1 + 0.5f  * (343.0f - c0);
    const float S_t2 = c2 + 0.25f * (343.0f - c0);
    const float inv  = 1.0f / 343.0f;
    const float ux   = S_t  * inv;
    const float uy   = c0   * inv;
    const float uxx  = S_t2 * inv;
    const float uxy  = c1   * inv;
    const float covn = 49.0f / 48.0f;   // WIN^2/(WIN^2-1)
    const float cc   = 0.00045f;        // (0.03*data_range)^2/2, data_range==1
    const float vx  = covn * (uxx - ux * ux);
    const float vy  = covn * (uy  - uy * uy);
    const float vxy = covn * (uxy - ux * uy);
    return (vxy + cc) / (vx * vy + cc);
}

__global__ __launch_bounds__(256, 4)
void structure_loss_main(const float* __restrict__ x,
                         const int* __restrict__ y,
                         double* __restrict__ acc) {
    // W-window sums, f16-packed SoA: (S_m,S_tm) half2 + S_t2m half = 14,784 B
    __shared__ __half2 sA01[IH * TW * IDU];
    __shared__ __half  sA2 [IH * TW * IDU];
    // vs (phase 0/A input) and sB (phase B/C) never live together: 17,664 B
    __shared__ union alignas(16) {
        __half vs[NCOL * ID];          // v = (y==cl ? +sig : -sig), f16
        float  sB[3][TH * TW * DPB];   // H-window sums, f32 SoA [ho][wo][dd(pad)]
    } u;
    __shared__ unsigned int yb[NITEMS];   // packed y bytes (4 d per u32): 4,704 B
    __shared__ float wsum[4];
    // total ~37.2 KB -> 4 blocks/CU

    const int dt = blockIdx.x;                 // 0..5
    const int wt = blockIdx.y;                 // 0..19
    const int z  = blockIdx.z;                 // 0..39 = b*HTILES + ht
    const int b  = z / HTILES;
    const int ht = z - b * HTILES;

    const int h0 = ht * TH, w0 = wt * TW, d0 = dt * TD;
    const int* yc = y + (size_t)b * (size_t)CSTRIDE;
    const int t = threadIdx.x;

    // ---- Hoisted staging addresses (class-invariant) ----
    int goff[5], lidx[5];
#pragma unroll
    for (int k = 0; k < 5; k++) {
        const int i = t + 256 * k;
        goff[k] = -1; lidx[k] = 0;
        if (i < NITEMS) {
            const int col = i / NV, q = i - col * NV;
            const int ih = col / IW, iw = col - ih * IW;
            const int h = min(h0 + ih, H - 1);
            const int w = min(w0 + iw, W - 1);
            const int dbase = d0 + 4 * q;
            lidx[k] = col * ID + 4 * q;
            if (dbase < DD) goff[k] = (h * W + w) * DD + dbase;
        }
    }

    // ---- Phase Y: stage packed y tile once (reused by all 4 classes) ----
#pragma unroll
    for (int k = 0; k < 5; k++) {
        const int i = t + 256 * k;
        if (i < NITEMS) {
            unsigned int pk = 0xFFFFFFFFu;             // OOB: matches no class
            if (goff[k] >= 0) {
                const int4 yv = *(const int4*)(yc + goff[k]);
                pk = (unsigned)(yv.x & 255) | ((unsigned)(yv.y & 255) << 8)
                   | ((unsigned)(yv.z & 255) << 16) | ((unsigned)(yv.w & 255) << 24);
            }
            yb[i] = pk;
        }
    }
    __syncthreads();

    float lsum = 0.f;

    for (int cl = 0; cl < 4; cl++) {
        const float* xc = x + ((size_t)b * 4 + cl) * (size_t)CSTRIDE;

        // ---- Phase 0: stage x channel, fuse with staged y. sign bit = mask ----
#pragma unroll
        for (int k = 0; k < 5; k++) {
            const int i = t + 256 * k;
            if (i < NITEMS) {
                Half4 hv;
                hv.x = hv.y = hv.z = hv.w = __float2half(0.f);
                if (goff[k] >= 0) {
                    const float4 xv = *(const float4*)(xc + goff[k]);
                    const unsigned int pk = yb[i];
                    const float s0 = 1.0f / (1.0f + __expf(-xv.x));
                    const float s1 = 1.0f / (1.0f + __expf(-xv.y));
                    const float s2 = 1.0f / (1.0f + __expf(-xv.z));
                    const float s3 = 1.0f / (1.0f + __expf(-xv.w));
                    hv.x = __float2half(((int)( pk        & 255u) == cl) ? s0 : -s0);
                    hv.y = __float2half(((int)((pk >>  8) & 255u) == cl) ? s1 : -s1);
                    hv.z = __float2half(((int)((pk >> 16) & 255u) == cl) ? s2 : -s2);
                    hv.w = __float2half(((int)((pk >> 24) & 255u) == cl) ? s3 : -s3);
                }
                *(Half4*)&u.vs[lidx[k]] = hv;
            }
        }
        __syncthreads();

        // ---- Phase A: W-window, slide over iw in registers. 308 items (ih,dd) ----
        for (int j = t; j < IH * IDU; j += 256) {
            const int ih = j / IDU, dd = j - ih * IDU;
            float v[IW];
            const int vbase = ih * IW * ID + dd;
#pragma unroll
            for (int iw = 0; iw < IW; iw++) v[iw] = __half2float(u.vs[vbase + iw * ID]);
            float s0 = 0.f, s1 = 0.f, s2 = 0.f;
#pragma unroll
            for (int iw = 0; iw < WINS; iw++) {
                const float p = fmaxf(v[iw], 0.f);
                s0 += (v[iw] > 0.f) ? 1.f : 0.f;
                s1 += p;
                s2 += p * v[iw];
            }
            int o = (ih * TW + 0) * IDU + dd;
            sA01[o] = __floats2half2_rn(s0, s1);
            sA2[o]  = __float2half_rn(s2);
#pragma unroll
            for (int wo = 1; wo < TW; wo++) {
                const float a = v[wo + 6], bb = v[wo - 1];
                const float pa_ = fmaxf(a, 0.f), pb_ = fmaxf(bb, 0.f);
                s0 += ((a > 0.f) ? 1.f : 0.f) - ((bb > 0.f) ? 1.f : 0.f);
                s1 += pa_ - pb_;
                s2 += pa_ * a - pb_ * bb;
                o += IDU;
                sA01[o] = __floats2half2_rn(s0, s1);
                sA2[o]  = __float2half_rn(s2);
            }
        }
        __syncthreads();   // sA ready; vs reads retired before sB overwrites union

        // ---- Phase B: H-window, slide 4 outputs. 352 items (hoHalf,wo,dd) ----
        for (int j = t; j < 2 * TW * IDU; j += 256) {
            const int dd = j % IDU;
            const int r  = j / IDU;
            const int wo = r & 7;
            const int ho0 = (r >> 3) * 4;          // 0 or 4
            float a0[10], a1[10], a2[10];
#pragma unroll
            for (int k = 0; k < 10; k++) {
                const int idx = ((ho0 + k) * TW + wo) * IDU + dd;
                const float2 f2 = __half22float2(sA01[idx]);
                a0[k] = f2.x; a1[k] = f2.y;
                a2[k] = __half2float(sA2[idx]);
            }
            float s0 = 0.f, s1 = 0.f, s2 = 0.f;
#pragma unroll
            for (int k = 0; k < WINS; k++) { s0 += a0[k]; s1 += a1[k]; s2 += a2[k]; }
            int o = (ho0 * TW + wo) * DPB + dd;
            u.sB[0][o] = s0; u.sB[1][o] = s1; u.sB[2][o] = s2;
#pragma unroll
            for (int k = 1; k < 4; k++) {
                s0 += a0[k + 6] - a0[k - 1];
                s1 += a1[k + 6] - a1[k - 1];
                s2 += a2[k + 6] - a2[k - 1];
                o += TW * DPB;
                u.sB[0][o] = s0; u.sB[1][o] = s1; u.sB[2][o] = s2;
            }
        }
        __syncthreads();

        // ---- Phase C: D-window, slide 8 outputs. 128 threads (ho,wo,dhalf) ----
        if (t < 128) {
            const int dhalf = t & 1;               // d outputs dhalf*8 .. +7
            const int wo = (t >> 1) & 7;
            const int ho = t >> 4;
            const int hg = h0 + ho, wg = w0 + wo;
            if (hg < HO && wg < WO) {
                const int base = (ho * TW + wo) * DPB + dhalf * 8;
                float b0[14], b1[14], b2[14];
#pragma unroll
                for (int k = 0; k < 14; k++) {
                    b0[k] = u.sB[0][base + k];
                    b1[k] = u.sB[1][base + k];
                    b2[k] = u.sB[2][base + k];
                }
                float s0 = 0.f, s1 = 0.f, s2 = 0.f;
#pragma unroll
                for (int k = 0; k < WINS; k++) { s0 += b0[k]; s1 += b1[k]; s2 += b2[k]; }
#pragma unroll
                for (int k = 0; k < 8; k++) {
                    if (k > 0) {
                        s0 += b0[k + 6] - b0[k - 1];
                        s1 += b1[k + 6] - b1[k - 1];
                        s2 += b2[k + 6] - b2[k - 1];
                    }
                    if (d0 + dhalf * 8 + k < DOUT) lsum += sval(s0, s1, s2);
                }
            }
        }
        __syncthreads();   // retire sB reads before next class overwrites union
    }

    // wave(64) shuffle reduce, then cross-wave via LDS, one atomic per block
#pragma unroll
    for (int off = 32; off > 0; off >>= 1) lsum += __shfl_down(lsum, off, 64);
    const int wave = t >> 6;
    if ((t & 63) == 0) wsum[wave] = lsum;
    __syncthreads();
    if (t == 0) {
        const float s = wsum[0] + wsum[1] + wsum[2] + wsum[3];
        atomicAdd(acc, (double)s);
    }
}

__global__ void structure_loss_finalize(const double* __restrict__ acc,
                                        float* __restrict__ out) {
    out[0] = 1.0f - (float)(acc[0] / 17075520.0);   // 8*154*154*90
}

extern "C" void kernel_launch(void* const* d_in, const int* in_sizes, int n_in,
                              void* d_out, int out_size, void* d_ws, size_t ws_size,
                              hipStream_t stream) {
    const float* x = (const float*)d_in[0];
    const int*   y = (const int*)d_in[1];
    double* acc = (double*)d_ws;

    hipMemsetAsync(d_ws, 0, sizeof(double), stream);

    dim3 grid(DTILES, WTILES, 2 * HTILES);   // (6, 20, 40) = 4,800 blocks
    structure_loss_main<<<grid, 256, 0, stream>>>(x, y, acc);
    structure_loss_finalize<<<1, 1, 0, stream>>>(acc, (float*)d_out);
}

// Round 7
// 234.925 us; speedup vs baseline: 2.5311x; 1.0974x over previous
//
#include <hip/hip_runtime.h>
#include <hip/hip_fp16.h>

// Problem geometry (fixed by reference)
#define WINS 7
#define H 160
#define W 160
#define DD 96
#define HO 154          // H - WINS + 1
#define WO 154
#define DOUT 90
#define CSTRIDE (H*W*DD)   // per-(b,c) channel stride

// Tile: 8x8x16 outputs, all 4 classes per block (y staged once)
#define TH 8
#define TW 8
#define TD 16
#define IH 14            // TH + WINS - 1
#define IW 14
#define NCOL (IH * IW)   // 196
#define IDU 22           // used d extent = TD + WINS - 1
#define ID 24            // staged d extent per column (halfs; 6 x half4)
#define NV 6             // half4-items / packed-y u32s per column
#define NITEMS (NCOL * NV)   // 1176
#define HTILES 20
#define WTILES 20
#define DTILES 6
#define DPB 23           // sB plane dd-stride (22 + 1 pad)

struct alignas(8) Half4 { __half x, y, z, w; };

__device__ __forceinline__ float sval(float c0, float c1, float c2) {
    // c0=S_m, c1=S_tm, c2=S_t2m over the 343-voxel window; t = m?sigmoid:0.5
    const float S_t  = c1 + 0.5f  * (343.0f - c0);
    const float S_t2 = c2 + 0.25f * (343.0f - c0);
    const float inv  = 1.0f / 343.0f;
    const float ux   = S_t  * inv;
    const float uy   = c0   * inv;
    const float uxx  = S_t2 * inv;
    const float uxy  = c1   * inv;
    const float covn = 49.0f / 48.0f;   // WIN^2/(WIN^2-1)
    const float cc   = 0.00045f;        // (0.03*data_range)^2/2, data_range==1
    const float vx  = covn * (uxx - ux * ux);
    const float vy  = covn * (uy  - uy * uy);
    const float vxy = covn * (uxy - ux * uy);
    // den >= ~3e-4 always (cc=4.5e-4, |vx*vy| tiny); fast rcp is safe
    return (vxy + cc) * __builtin_amdgcn_rcpf(vx * vy + cc);
}

__global__ __launch_bounds__(256, 5)
void structure_loss_main(const float* __restrict__ x,
                         const int* __restrict__ y,
                         double* __restrict__ acc) {
    // W-window sums, f16-packed SoA: (S_m,S_tm) half2 + S_t2m half = 14,784 B
    __shared__ __half2 sA01[IH * TW * IDU];
    __shared__ __half  sA2 [IH * TW * IDU];
    // vs (phase 0/A input) and sB (phase B/C) never live together: 9,408 B
    __shared__ union alignas(16) {
        __half vs[NCOL * ID];          // v = (y==cl ? +sig : -sig), f16
        struct {
            __half2 b01[TH * TW * DPB];   // (S_m, S_tm) H-window sums
            __half  b2 [TH * TW * DPB];   // S_t2m
        } sb;
    } u;
    __shared__ unsigned int yb[NITEMS];   // packed y bytes (4 d per u32): 4,704 B
    __shared__ float wsum[4];
    // total ~29 KB -> 5 blocks/CU

    const int dt = blockIdx.x;                 // 0..5
    const int wt = blockIdx.y;                 // 0..19
    const int z  = blockIdx.z;                 // 0..39 = b*HTILES + ht
    const int b  = z / HTILES;
    const int ht = z - b * HTILES;

    const int h0 = ht * TH, w0 = wt * TW, d0 = dt * TD;
    const int* yc = y + (size_t)b * (size_t)CSTRIDE;
    const int t = threadIdx.x;

    // ---- Hoisted staging addresses (class-invariant) ----
    int goff[5], lidx[5];
#pragma unroll
    for (int k = 0; k < 5; k++) {
        const int i = t + 256 * k;
        goff[k] = -1; lidx[k] = 0;
        if (i < NITEMS) {
            const int col = i / NV, q = i - col * NV;
            const int ih = col / IW, iw = col - ih * IW;
            const int h = min(h0 + ih, H - 1);
            const int w = min(w0 + iw, W - 1);
            const int dbase = d0 + 4 * q;
            lidx[k] = col * ID + 4 * q;
            if (dbase < DD) goff[k] = (h * W + w) * DD + dbase;
        }
    }

    // ---- Phase Y: stage packed y tile once (reused by all 4 classes) ----
#pragma unroll
    for (int k = 0; k < 5; k++) {
        const int i = t + 256 * k;
        if (i < NITEMS) {
            unsigned int pk = 0xFFFFFFFFu;             // OOB: matches no class
            if (goff[k] >= 0) {
                const int4 yv = *(const int4*)(yc + goff[k]);
                pk = (unsigned)(yv.x & 255) | ((unsigned)(yv.y & 255) << 8)
                   | ((unsigned)(yv.z & 255) << 16) | ((unsigned)(yv.w & 255) << 24);
            }
            yb[i] = pk;
        }
    }
    __syncthreads();

    float lsum = 0.f;

    for (int cl = 0; cl < 4; cl++) {
        const float* xc = x + ((size_t)b * 4 + cl) * (size_t)CSTRIDE;

        // ---- Phase 0: stage x channel, fuse with staged y. sign bit = mask ----
#pragma unroll
        for (int k = 0; k < 5; k++) {
            const int i = t + 256 * k;
            if (i < NITEMS) {
                Half4 hv;
                hv.x = hv.y = hv.z = hv.w = __float2half(0.f);
                if (goff[k] >= 0) {
                    const float4 xv = *(const float4*)(xc + goff[k]);
                    const unsigned int pk = yb[i];
                    const float s0 = 1.0f / (1.0f + __expf(-xv.x));
                    const float s1 = 1.0f / (1.0f + __expf(-xv.y));
                    const float s2 = 1.0f / (1.0f + __expf(-xv.z));
                    const float s3 = 1.0f / (1.0f + __expf(-xv.w));
                    hv.x = __float2half(((int)( pk        & 255u) == cl) ? s0 : -s0);
                    hv.y = __float2half(((int)((pk >>  8) & 255u) == cl) ? s1 : -s1);
                    hv.z = __float2half(((int)((pk >> 16) & 255u) == cl) ? s2 : -s2);
                    hv.w = __float2half(((int)((pk >> 24) & 255u) == cl) ? s3 : -s3);
                }
                *(Half4*)&u.vs[lidx[k]] = hv;
            }
        }
        __syncthreads();

        // ---- Phase A: W-window, slide over iw in registers. 308 items (ih,dd) ----
        for (int j = t; j < IH * IDU; j += 256) {
            const int ih = j / IDU, dd = j - ih * IDU;
            float v[IW];
            const int vbase = ih * IW * ID + dd;
#pragma unroll
            for (int iw = 0; iw < IW; iw++) v[iw] = __half2float(u.vs[vbase + iw * ID]);
            float s0 = 0.f, s1 = 0.f, s2 = 0.f;
#pragma unroll
            for (int iw = 0; iw < WINS; iw++) {
                const float p = fmaxf(v[iw], 0.f);
                s0 += (v[iw] > 0.f) ? 1.f : 0.f;
                s1 += p;
                s2 += p * v[iw];
            }
            int o = (ih * TW + 0) * IDU + dd;
            sA01[o] = __floats2half2_rn(s0, s1);
            sA2[o]  = __float2half_rn(s2);
#pragma unroll
            for (int wo = 1; wo < TW; wo++) {
                const float a = v[wo + 6], bb = v[wo - 1];
                const float pa_ = fmaxf(a, 0.f), pb_ = fmaxf(bb, 0.f);
                s0 += ((a > 0.f) ? 1.f : 0.f) - ((bb > 0.f) ? 1.f : 0.f);
                s1 += pa_ - pb_;
                s2 += pa_ * a - pb_ * bb;
                o += IDU;
                sA01[o] = __floats2half2_rn(s0, s1);
                sA2[o]  = __float2half_rn(s2);
            }
        }
        __syncthreads();   // sA ready; vs reads retired before sb overwrites union

        // ---- Phase B: H-window, slide 4 outputs. 352 items (hoHalf,wo,dd) ----
        for (int j = t; j < 2 * TW * IDU; j += 256) {
            const int dd = j % IDU;
            const int r  = j / IDU;
            const int wo = r & 7;
            const int ho0 = (r >> 3) * 4;          // 0 or 4
            float a0[10], a1[10], a2[10];
#pragma unroll
            for (int k = 0; k < 10; k++) {
                const int idx = ((ho0 + k) * TW + wo) * IDU + dd;
                const float2 f2 = __half22float2(sA01[idx]);
                a0[k] = f2.x; a1[k] = f2.y;
                a2[k] = __half2float(sA2[idx]);
            }
            float s0 = 0.f, s1 = 0.f, s2 = 0.f;
#pragma unroll
            for (int k = 0; k < WINS; k++) { s0 += a0[k]; s1 += a1[k]; s2 += a2[k]; }
            int o = (ho0 * TW + wo) * DPB + dd;
            u.sb.b01[o] = __floats2half2_rn(s0, s1);
            u.sb.b2[o]  = __float2half_rn(s2);
#pragma unroll
            for (int k = 1; k < 4; k++) {
                s0 += a0[k + 6] - a0[k - 1];
                s1 += a1[k + 6] - a1[k - 1];
                s2 += a2[k + 6] - a2[k - 1];
                o += TW * DPB;
                u.sb.b01[o] = __floats2half2_rn(s0, s1);
                u.sb.b2[o]  = __float2half_rn(s2);
            }
        }
        __syncthreads();

        // ---- Phase C: D-window, slide 4 outputs. 256 threads (ho,wo,dq) ----
        {
            const int dq = t & 3;                  // d outputs dq*4 .. dq*4+3
            const int wo = (t >> 2) & 7;
            const int ho = t >> 5;
            const int hg = h0 + ho, wg = w0 + wo;
            if (hg < HO && wg < WO) {
                const int base = (ho * TW + wo) * DPB + dq * 4;
                float b0[10], b1[10], b2[10];
#pragma unroll
                for (int k = 0; k < 10; k++) {
                    const float2 f2 = __half22float2(u.sb.b01[base + k]);
                    b0[k] = f2.x; b1[k] = f2.y;
                    b2[k] = __half2float(u.sb.b2[base + k]);
                }
                float s0 = 0.f, s1 = 0.f, s2 = 0.f;
#pragma unroll
                for (int k = 0; k < WINS; k++) { s0 += b0[k]; s1 += b1[k]; s2 += b2[k]; }
                const int dg = d0 + dq * 4;
#pragma unroll
                for (int k = 0; k < 4; k++) {
                    if (k > 0) {
                        s0 += b0[k + 6] - b0[k - 1];
                        s1 += b1[k + 6] - b1[k - 1];
                        s2 += b2[k + 6] - b2[k - 1];
                    }
                    if (dg + k < DOUT) lsum += sval(s0, s1, s2);
                }
            }
        }
        __syncthreads();   // retire sb reads before next class overwrites union
    }

    // wave(64) shuffle reduce, then cross-wave via LDS, one atomic per block
#pragma unroll
    for (int off = 32; off > 0; off >>= 1) lsum += __shfl_down(lsum, off, 64);
    const int wave = t >> 6;
    if ((t & 63) == 0) wsum[wave] = lsum;
    __syncthreads();
    if (t == 0) {
        const float s = wsum[0] + wsum[1] + wsum[2] + wsum[3];
        atomicAdd(acc, (double)s);
    }
}

__global__ void structure_loss_finalize(const double* __restrict__ acc,
                                        float* __restrict__ out) {
    out[0] = 1.0f - (float)(acc[0] / 17075520.0);   // 8*154*154*90
}

extern "C" void kernel_launch(void* const* d_in, const int* in_sizes, int n_in,
                              void* d_out, int out_size, void* d_ws, size_t ws_size,
                              hipStream_t stream) {
    const float* x = (const float*)d_in[0];
    const int*   y = (const int*)d_in[1];
    double* acc = (double*)d_ws;

    hipMemsetAsync(d_ws, 0, sizeof(double), stream);

    dim3 grid(DTILES, WTILES, 2 * HTILES);   // (6, 20, 40) = 4,800 blocks
    structure_loss_main<<<grid, 256, 0, stream>>>(x, y, acc);
    structure_loss_finalize<<<1, 1, 0, stream>>>(acc, (float*)d_out);
}